// Round 3
// baseline (268.057 us; speedup 1.0000x reference)
//
#include <hip/hip_runtime.h>
#include <cfloat>

#define B_ 32
#define N_ 1000
#define K_ 10
#define H_ 128
#define C_ 2
#define NFEAT 43    // 20 sortedX + 20 sortedY + 2 coords + 1 bias
#define QPB 32      // queries per block
#define TPQ 8       // threads per query
#define G_ 16       // grid cells per axis
#define CW (1.0f / 16.0f)
#define RING0 2     // initial box half-width in cells (5x5)
#define PSTR 81     // u64 stride per query in publish scratch (81*2 % 32 != 0 -> bank spread)

// ws layout (bytes): [0,22016) Meff | [22016,278016) spts float2 | [278016,406016) skey int
//                    | [406016,438912) cellstart int
#define WS_MEFF   0
#define WS_SPTS   22016
#define WS_SKEY   278016
#define WS_CSTART 406016
#define WS_NEED   438912

// ---------------------------------------------------------------------------
// Kernel A: fused affine map M[43][128] (folds Wx,Wy,W1,W2,biases).
// ---------------------------------------------------------------------------
__global__ __launch_bounds__(H_) void build_meff(
    const float* __restrict__ Wx, const float* __restrict__ bx,
    const float* __restrict__ Wy, const float* __restrict__ by,
    const float* __restrict__ W1, const float* __restrict__ b1,
    const float* __restrict__ W2, const float* __restrict__ b2,
    float* __restrict__ M) {
  const int r = blockIdx.x;
  const int g = threadIdx.x;
  float acc = 0.f;
  if (r < 40) {
    const int rp = (r < 20) ? r : r - 20;
    const float* W = (r < 20) ? Wx : Wy;
    const int k = rp >> 1;
    const int c = rp & 1;
    const float* Wcol = W + c * K_ + k;     // h-stride = C_*K_
    for (int h = 0; h < H_; ++h)
      acc = fmaf(Wcol[h * C_ * K_], W2[h * H_ + g], acc);
  } else if (r < 42) {
    acc = W1[(r - 40) * H_ + g];
  } else {
    for (int h = 0; h < H_; ++h)
      acc = fmaf(bx[h] + by[h], W2[h * H_ + g], acc);
    acc += b1[g] + b2[g];
  }
  M[r * H_ + g] = acc;
}

// ---------------------------------------------------------------------------
// Kernel B: per-batch counting sort of points into 16x16 cells.
// grid = 32 blocks (one per batch), block = 256 (== G_*G_).
// ---------------------------------------------------------------------------
__global__ __launch_bounds__(256) void build_grid(
    const float* __restrict__ x, float2* __restrict__ spts_g,
    int* __restrict__ skey_g, int* __restrict__ cstart_g) {
  const int b = blockIdx.x, tid = threadIdx.x;
  __shared__ float2 p[N_];        // 8 KB
  __shared__ short  cidv[N_];     // 2 KB
  __shared__ int    hist[G_ * G_], scn[G_ * G_], cur[G_ * G_];

  const float2* xb = (const float2*)(x + (size_t)b * N_ * C_);
  hist[tid] = 0;
  __syncthreads();
  for (int i = tid; i < N_; i += 256) {
    float2 v = xb[i];
    p[i] = v;
    int cxx = min(G_ - 1, max(0, (int)(v.x * (float)G_)));
    int cyy = min(G_ - 1, max(0, (int)(v.y * (float)G_)));
    int c = cyy * G_ + cxx;
    cidv[i] = (short)c;
    atomicAdd(&hist[c], 1);
  }
  __syncthreads();
  const int v = hist[tid];
  scn[tid] = v;
  __syncthreads();
  for (int off = 1; off < G_ * G_; off <<= 1) {     // Hillis-Steele inclusive scan
    int add = (tid >= off) ? scn[tid - off] : 0;
    __syncthreads();
    scn[tid] += add;
    __syncthreads();
  }
  const int excl = scn[tid] - v;
  cur[tid] = excl;
  cstart_g[b * (G_ * G_ + 1) + tid] = excl;
  if (tid == 0) cstart_g[b * (G_ * G_ + 1) + G_ * G_] = N_;
  __syncthreads();
  for (int i = tid; i < N_; i += 256) {
    int c = cidv[i];
    int pos = atomicAdd(&cur[c], 1);
    spts_g[b * N_ + pos] = p[i];
    skey_g[b * N_ + pos] = (i << 16) | pos;   // (orig_idx:16 | sorted_pos:16)
  }
}

// ---------------------------------------------------------------------------
// Kernel C: grid-pruned exact KNN + stable coord sorts + fused affine.
// Queries processed in sorted (cell-major) order for spatial coherence.
// grid = (32 chunks, 32 batches), block = 256 (32 queries x 8 threads).
// ---------------------------------------------------------------------------
__global__ __launch_bounds__(QPB * TPQ, 4) void conv_knn(
    const float2* __restrict__ spts_g, const int* __restrict__ skey_g,
    const int* __restrict__ cstart_g, const float* __restrict__ Meff,
    float* __restrict__ out) {
  __shared__ float2 spts[N_];                 // 8 KB  sorted coords
  __shared__ int    skey[N_];                 // 4 KB  (orig<<16)|spos
  __shared__ int    cstart[G_ * G_ + 1];      // 1 KB
  __shared__ int    midx[QPB * K_];           // merged keylos
  __shared__ int    qdone[QPB];
  __shared__ int    bflag;
  __shared__ __align__(16) float smem[NFEAT * H_];  // 22 KB: u64 publish scratch, later M

  const int b = blockIdx.y, tid = threadIdx.x;
  const int q = tid >> 3, t = tid & 7;
  const int sbase = blockIdx.x * QPB;
  const int s = sbase + q;
  const bool valid = (s < N_);

  const float2* spg = spts_g + (size_t)b * N_;
  const int*    skg = skey_g + (size_t)b * N_;
  for (int i = tid; i < N_; i += QPB * TPQ) { spts[i] = spg[i]; skey[i] = skg[i]; }
  for (int i = tid; i < G_ * G_ + 1; i += QPB * TPQ)
    cstart[i] = cstart_g[b * (G_ * G_ + 1) + i];
  if (tid < QPB) qdone[tid] = (sbase + tid >= N_) ? 1 : 0;
  __syncthreads();

  float px = 0.f, py = 0.f;
  int cx = 0, cy = 0;
  if (valid) {
    px = spts[s].x; py = spts[s].y;
    cx = min(G_ - 1, max(0, (int)(px * (float)G_)));
    cy = min(G_ - 1, max(0, (int)(py * (float)G_)));
  }

  unsigned long long bk[K_];
#pragma unroll
  for (int k = 0; k < K_; ++k) bk[k] = ~0ull;

  unsigned long long* pub = (unsigned long long*)smem;
  bool qd = !valid;
  int ox0 = 999, ox1 = -999, oy0 = 999, oy1 = -999;

  auto insert = [&](int j) {
    float2 pp = spts[j];
    float dx = __fsub_rn(px, pp.x);
    float dy = __fsub_rn(py, pp.y);
    float dd = __fadd_rn(__fmul_rn(dx, dx), __fmul_rn(dy, dy));   // == reference rounding
    unsigned long long key =
        ((unsigned long long)__float_as_uint(dd) << 32) | (unsigned)skey[j];
    bool c[K_];
#pragma unroll
    for (int kk = 0; kk < K_; ++kk) c[kk] = key < bk[kk];
#pragma unroll
    for (int kk = K_ - 1; kk >= 1; --kk)
      bk[kk] = c[kk - 1] ? bk[kk - 1] : (c[kk] ? key : bk[kk]);
    bk[0] = c[0] ? key : bk[0];
  };

  // ---- adaptive ring loop (block-uniform; exact termination criterion) ----
  for (int ring = RING0;; ++ring) {
    const int X0 = max(cx - ring, 0), X1 = min(cx + ring, G_ - 1);
    const int Y0 = max(cy - ring, 0), Y1 = min(cy + ring, G_ - 1);
    if (!qd) {
      for (int yy = Y0; yy <= Y1; ++yy) {
        int a0, a1, c0 = 1, c1 = 0;
        if (yy < oy0 || yy > oy1) { a0 = X0; a1 = X1; }          // full new row
        else { a0 = X0; a1 = ox0 - 1; c0 = ox1 + 1; c1 = X1; }   // side strips
        if (a1 >= a0) {
          int s0 = cstart[yy * G_ + a0], s1 = cstart[yy * G_ + a1 + 1];
          for (int j = s0 + t; j < s1; j += TPQ) insert(j);
        }
        if (c1 >= c0) {
          int s0 = cstart[yy * G_ + c0], s1 = cstart[yy * G_ + c1 + 1];
          for (int j = s0 + t; j < s1; j += TPQ) insert(j);
        }
      }
      ox0 = X0; ox1 = X1; oy0 = Y0; oy1 = Y1;
#pragma unroll
      for (int e = 0; e < K_; ++e) pub[q * PSTR + t * K_ + e] = bk[e];
    }
    __syncthreads();
    if (t == 0 && !qd) {
      int cc[TPQ];
#pragma unroll
      for (int tt = 0; tt < TPQ; ++tt) cc[tt] = 0;
      unsigned long long last = 0ull;
      int lk[K_];
      const int base = q * PSTR;
#pragma unroll
      for (int ss = 0; ss < K_; ++ss) {
        unsigned long long best = ~0ull; int bt = 0;
#pragma unroll
        for (int tt = 0; tt < TPQ; ++tt) {
          int cct = cc[tt];
          unsigned long long h = pub[base + tt * K_ + (cct < K_ ? cct : K_ - 1)];
          if (cct >= K_) h = ~0ull;
          bool take = h < best;
          best = take ? h : best;
          bt = take ? tt : bt;
        }
        lk[ss] = (int)(unsigned)(best & 0xffffffffull);
        last = best;
#pragma unroll
        for (int tt = 0; tt < TPQ; ++tt) cc[tt] += (bt == tt) ? 1 : 0;
      }
      const bool have10 = (last != ~0ull);
      const float tau = __uint_as_float((unsigned)(last >> 32));
      float R = 1e30f;
      if (X0 > 0)      R = fminf(R, px - (float)X0 * CW);
      if (X1 < G_ - 1) R = fminf(R, (float)(X1 + 1) * CW - px);
      if (Y0 > 0)      R = fminf(R, py - (float)Y0 * CW);
      if (Y1 < G_ - 1) R = fminf(R, (float)(Y1 + 1) * CW - py);
      const bool fullg = (X0 == 0) && (X1 == G_ - 1) && (Y0 == 0) && (Y1 == G_ - 1);
      const float Rs = R - 1e-6f;   // safety vs. cell-assignment & squaring rounding
      const bool done = fullg || (have10 && Rs > 0.f && tau < Rs * Rs);
      qdone[q] = done ? 1 : 0;
      if (done) {
#pragma unroll
        for (int k = 0; k < K_; ++k) midx[q * K_ + k] = lk[k];
      }
    }
    __syncthreads();
    if (tid == 0) {
      int f = 0;
      for (int qq = 0; qq < QPB; ++qq) f |= (qdone[qq] == 0) ? 1 : 0;
      bflag = f;
    }
    __syncthreads();
    qd = (qdone[q] != 0);
    if (!bflag) break;
  }

  // ---- load M (overwrites publish scratch; all lists consumed) ----
  for (int i = tid; i < NFEAT * H_; i += QPB * TPQ) smem[i] = Meff[i];

  // ---- gather coords + stable bubble sorts + feature vector ----
  float feat[NFEAT] = {};
  if (valid) {
    float cx1[K_], cy1[K_], cx2[K_], cy2[K_];
#pragma unroll
    for (int k = 0; k < K_; ++k) {
      const int spos = midx[q * K_ + k] & 0xffff;
      const float2 c = spts[spos];
      cx1[k] = c.x; cy1[k] = c.y;
      cx2[k] = c.x; cy2[k] = c.y;
    }
#pragma unroll
    for (int p = 0; p < K_ - 1; ++p) {
#pragma unroll
      for (int u = 0; u < K_ - 1 - p; ++u) {
        const bool sw = cx1[u + 1] < cx1[u];   // strict => stable
        const float tx = sw ? cx1[u] : cx1[u + 1];
        const float ty = sw ? cy1[u] : cy1[u + 1];
        cx1[u]     = sw ? cx1[u + 1] : cx1[u];
        cy1[u]     = sw ? cy1[u + 1] : cy1[u];
        cx1[u + 1] = tx; cy1[u + 1] = ty;
      }
    }
#pragma unroll
    for (int p = 0; p < K_ - 1; ++p) {
#pragma unroll
      for (int u = 0; u < K_ - 1 - p; ++u) {
        const bool sw = cy2[u + 1] < cy2[u];
        const float tx = sw ? cx2[u] : cx2[u + 1];
        const float ty = sw ? cy2[u] : cy2[u + 1];
        cx2[u]     = sw ? cx2[u + 1] : cx2[u];
        cy2[u]     = sw ? cy2[u + 1] : cy2[u];
        cx2[u + 1] = tx; cy2[u + 1] = ty;
      }
    }
#pragma unroll
    for (int k = 0; k < K_; ++k) {
      feat[2 * k]          = cx1[k];
      feat[2 * k + 1]      = cy1[k];
      feat[20 + 2 * k]     = cx2[k];
      feat[20 + 2 * k + 1] = cy2[k];
    }
    feat[40] = px;
    feat[41] = py;
    feat[42] = 1.f;
  }
  __syncthreads();

  // ---- fused affine, remapped: each thread = 4 queries x 4 outputs ----
  // qset = tid>>5 covers queries 4*qset..+3 (same wave as their feat lanes);
  // gset = tid&31 covers g = 4*gset..+3 (float4 M reads + float4 stores).
  const int qset = tid >> 5;
  const int gset = tid & 31;
  float4 acc[4];
#pragma unroll
  for (int j = 0; j < 4; ++j) acc[j] = make_float4(0.f, 0.f, 0.f, 0.f);
#pragma unroll
  for (int r = 0; r < NFEAT; ++r) {
    const float4 m4 = *(const float4*)&smem[r * H_ + gset * 4];
#pragma unroll
    for (int j = 0; j < 4; ++j) {
      const int lsrc = ((qset & 1) * 4 + j) * 8;   // a lane of target query in this wave
      const float fr = __shfl(feat[r], lsrc, 64);
      acc[j].x = fmaf(fr, m4.x, acc[j].x);
      acc[j].y = fmaf(fr, m4.y, acc[j].y);
      acc[j].z = fmaf(fr, m4.z, acc[j].z);
      acc[j].w = fmaf(fr, m4.w, acc[j].w);
    }
  }
#pragma unroll
  for (int j = 0; j < 4; ++j) {
    const int qtar = qset * 4 + j;
    const int star = sbase + qtar;
    if (star < N_) {
      const int otar = skey[star] >> 16;
      *(float4*)&out[((size_t)(b * N_ + otar)) * H_ + gset * 4] = acc[j];
    }
  }
}

// ---------------------------------------------------------------------------
// Fallback (round-2 kernel) if workspace is too small for the grid path.
// ---------------------------------------------------------------------------
#define LSTRIDE 170
__global__ __launch_bounds__(QPB * TPQ, 4) void conv_emb_fb(
    const float* __restrict__ x, const float* __restrict__ Meff,
    float* __restrict__ out) {
  __shared__ float2 pts[N_];
  __shared__ float  smem[NFEAT * H_];
  __shared__ int    midx[QPB * K_];

  const int b   = blockIdx.y;
  const int tid = threadIdx.x;
  const int q   = tid >> 3;
  const int t   = tid & 7;
  const int n   = blockIdx.x * QPB + q;
  const bool valid = (n < N_);

  const float2* xb = (const float2*)(x + (size_t)b * N_ * C_);
  for (int i = tid; i < N_; i += QPB * TPQ) pts[i] = xb[i];
  __syncthreads();

  float px = 0.f, py = 0.f;
  if (valid) { px = pts[n].x; py = pts[n].y; }

  float bd[K_]; int bi[K_];
#pragma unroll
  for (int k = 0; k < K_; ++k) { bd[k] = FLT_MAX; bi[k] = 0; }

#pragma unroll 2
  for (int m = 0; m < N_ / TPQ; ++m) {
    const int j = t + m * TPQ;
    const float2 p = pts[j];
    const float dx = __fsub_rn(px, p.x);
    const float dy = __fsub_rn(py, p.y);
    const float d  = __fadd_rn(__fmul_rn(dx, dx), __fmul_rn(dy, dy));
    bool c[K_];
#pragma unroll
    for (int s = 0; s < K_; ++s) c[s] = d < bd[s];
#pragma unroll
    for (int s = K_ - 1; s >= 1; --s) {
      bd[s] = c[s - 1] ? bd[s - 1] : (c[s] ? d : bd[s]);
      bi[s] = c[s - 1] ? bi[s - 1] : (c[s] ? j : bi[s]);
    }
    bd[0] = c[0] ? d : bd[0];
    bi[0] = c[0] ? j : bi[0];
  }

  const int lbase = q * LSTRIDE + t * 2 * K_;
#pragma unroll
  for (int e = 0; e < K_; ++e) {
    smem[lbase + 2 * e]     = bd[e];
    smem[lbase + 2 * e + 1] = __int_as_float(bi[e]);
  }
  __syncthreads();

  if (t == 0 && valid) {
    int cc[TPQ];
#pragma unroll
    for (int tt = 0; tt < TPQ; ++tt) cc[tt] = 0;
    const int mb = q * LSTRIDE;
#pragma unroll
    for (int s = 0; s < K_; ++s) {
      float bdv = FLT_MAX; int biv = 0x7fffffff; int bt = 0;
#pragma unroll
      for (int tt = 0; tt < TPQ; ++tt) {
        const int off = mb + tt * 2 * K_ + cc[tt] * 2;
        const float hd = smem[off];
        const int   hi = __float_as_int(smem[off + 1]);
        const bool take = (hd < bdv) || ((hd == bdv) && (hi < biv));
        bdv = take ? hd : bdv;
        biv = take ? hi : biv;
        bt  = take ? tt : bt;
      }
      midx[q * K_ + s] = biv;
#pragma unroll
      for (int tt = 0; tt < TPQ; ++tt) cc[tt] += (bt == tt) ? 1 : 0;
    }
  }
  __syncthreads();

  int ridx[K_];
  if (valid) {
#pragma unroll
    for (int k = 0; k < K_; ++k) ridx[k] = midx[q * K_ + k];
  }
  for (int i = tid; i < NFEAT * H_; i += QPB * TPQ) smem[i] = Meff[i];

  float feat[NFEAT];
  if (valid) {
    float cx1[K_], cy1[K_], cx2[K_], cy2[K_];
#pragma unroll
    for (int k = 0; k < K_; ++k) {
      const float2 c = pts[ridx[k]];
      cx1[k] = c.x; cy1[k] = c.y;
      cx2[k] = c.x; cy2[k] = c.y;
    }
#pragma unroll
    for (int p = 0; p < K_ - 1; ++p) {
#pragma unroll
      for (int s2 = 0; s2 < K_ - 1 - p; ++s2) {
        const bool sw = cx1[s2 + 1] < cx1[s2];
        const float tx = sw ? cx1[s2] : cx1[s2 + 1];
        const float ty = sw ? cy1[s2] : cy1[s2 + 1];
        cx1[s2]     = sw ? cx1[s2 + 1] : cx1[s2];
        cy1[s2]     = sw ? cy1[s2 + 1] : cy1[s2];
        cx1[s2 + 1] = tx; cy1[s2 + 1] = ty;
      }
    }
#pragma unroll
    for (int p = 0; p < K_ - 1; ++p) {
#pragma unroll
      for (int s2 = 0; s2 < K_ - 1 - p; ++s2) {
        const bool sw = cy2[s2 + 1] < cy2[s2];
        const float tx = sw ? cx2[s2] : cx2[s2 + 1];
        const float ty = sw ? cy2[s2] : cy2[s2 + 1];
        cx2[s2]     = sw ? cx2[s2 + 1] : cx2[s2];
        cy2[s2]     = sw ? cy2[s2 + 1] : cy2[s2];
        cx2[s2 + 1] = tx; cy2[s2 + 1] = ty;
      }
    }
#pragma unroll
    for (int k = 0; k < K_; ++k) {
      feat[2 * k]          = cx1[k];
      feat[2 * k + 1]      = cy1[k];
      feat[20 + 2 * k]     = cx2[k];
      feat[20 + 2 * k + 1] = cy2[k];
    }
    feat[40] = px;
    feat[41] = py;
    feat[42] = 1.f;
  }
  __syncthreads();

  if (valid) {
    float* op = out + ((size_t)(b * N_ + n)) * H_;
#pragma unroll 2
    for (int gi = 0; gi < H_ / TPQ; ++gi) {
      const int g = gi * TPQ + t;
      float acc = 0.f;
#pragma unroll
      for (int r = 0; r < NFEAT; ++r)
        acc = fmaf(feat[r], smem[r * H_ + g], acc);
      op[g] = acc;
    }
  }
}

extern "C" void kernel_launch(void* const* d_in, const int* in_sizes, int n_in,
                              void* d_out, int out_size, void* d_ws, size_t ws_size,
                              hipStream_t stream) {
  const float* x  = (const float*)d_in[0];
  const float* Wx = (const float*)d_in[1];
  const float* bx = (const float*)d_in[2];
  const float* Wy = (const float*)d_in[3];
  const float* by = (const float*)d_in[4];
  const float* W1 = (const float*)d_in[5];
  const float* b1 = (const float*)d_in[6];
  const float* W2 = (const float*)d_in[7];
  const float* b2 = (const float*)d_in[8];
  float* o = (float*)d_out;

  char* ws = (char*)d_ws;
  float* Meff = (float*)(ws + WS_MEFF);

  build_meff<<<dim3(NFEAT), dim3(H_), 0, stream>>>(Wx, bx, Wy, by, W1, b1, W2, b2, Meff);

  if (ws_size >= WS_NEED) {
    float2* spts_g  = (float2*)(ws + WS_SPTS);
    int*   skey_g   = (int*)(ws + WS_SKEY);
    int*   cstart_g = (int*)(ws + WS_CSTART);
    build_grid<<<dim3(B_), dim3(256), 0, stream>>>(x, spts_g, skey_g, cstart_g);
    conv_knn<<<dim3((N_ + QPB - 1) / QPB, B_), dim3(QPB * TPQ), 0, stream>>>(
        spts_g, skey_g, cstart_g, Meff, o);
  } else {
    conv_emb_fb<<<dim3((N_ + QPB - 1) / QPB, B_), dim3(QPB * TPQ), 0, stream>>>(x, Meff, o);
  }
}

// Round 4
// 262.065 us; speedup vs baseline: 1.0229x; 1.0229x over previous
//
#include <hip/hip_runtime.h>
#include <cfloat>

#define B_ 32
#define N_ 1000
#define K_ 10
#define H_ 128
#define C_ 2
#define NFEAT 43    // 20 sortedX + 20 sortedY + 2 coords + 1 bias
#define QPB 32      // queries per block
#define TPQ 8       // threads per query
#define G_ 16       // grid cells per axis
#define CW (1.0f / 16.0f)
#define RING0 2     // box half-width in cells (5x5)
#define PSTR 81     // u64 stride per query in publish scratch

// ws layout (bytes): [0,22016) Meff | [22016,278016) spts float2 | [278016,406016) skey int
//                    | [406016,438912) cellstart int
#define WS_MEFF   0
#define WS_SPTS   22016
#define WS_SKEY   278016
#define WS_CSTART 406016
#define WS_NEED   438912

// ---------------------------------------------------------------------------
// Kernel A: fused affine map M[43][128] (folds Wx,Wy,W1,W2,biases).
// ---------------------------------------------------------------------------
__global__ __launch_bounds__(H_) void build_meff(
    const float* __restrict__ Wx, const float* __restrict__ bx,
    const float* __restrict__ Wy, const float* __restrict__ by,
    const float* __restrict__ W1, const float* __restrict__ b1,
    const float* __restrict__ W2, const float* __restrict__ b2,
    float* __restrict__ M) {
  const int r = blockIdx.x;
  const int g = threadIdx.x;
  float acc = 0.f;
  if (r < 40) {
    const int rp = (r < 20) ? r : r - 20;
    const float* W = (r < 20) ? Wx : Wy;
    const int k = rp >> 1;
    const int c = rp & 1;
    const float* Wcol = W + c * K_ + k;     // h-stride = C_*K_
    for (int h = 0; h < H_; ++h)
      acc = fmaf(Wcol[h * C_ * K_], W2[h * H_ + g], acc);
  } else if (r < 42) {
    acc = W1[(r - 40) * H_ + g];
  } else {
    for (int h = 0; h < H_; ++h)
      acc = fmaf(bx[h] + by[h], W2[h * H_ + g], acc);
    acc += b1[g] + b2[g];
  }
  M[r * H_ + g] = acc;
}

// ---------------------------------------------------------------------------
// Kernel B: per-batch counting sort of points into 16x16 cells.
// ---------------------------------------------------------------------------
__global__ __launch_bounds__(256) void build_grid(
    const float* __restrict__ x, float2* __restrict__ spts_g,
    int* __restrict__ skey_g, int* __restrict__ cstart_g) {
  const int b = blockIdx.x, tid = threadIdx.x;
  __shared__ float2 p[N_];
  __shared__ short  cidv[N_];
  __shared__ int    hist[G_ * G_], scn[G_ * G_], cur[G_ * G_];

  const float2* xb = (const float2*)(x + (size_t)b * N_ * C_);
  hist[tid] = 0;
  __syncthreads();
  for (int i = tid; i < N_; i += 256) {
    float2 v = xb[i];
    p[i] = v;
    int cxx = min(G_ - 1, max(0, (int)(v.x * (float)G_)));
    int cyy = min(G_ - 1, max(0, (int)(v.y * (float)G_)));
    int c = cyy * G_ + cxx;
    cidv[i] = (short)c;
    atomicAdd(&hist[c], 1);
  }
  __syncthreads();
  const int v = hist[tid];
  scn[tid] = v;
  __syncthreads();
  for (int off = 1; off < G_ * G_; off <<= 1) {
    int add = (tid >= off) ? scn[tid - off] : 0;
    __syncthreads();
    scn[tid] += add;
    __syncthreads();
  }
  const int excl = scn[tid] - v;
  cur[tid] = excl;
  cstart_g[b * (G_ * G_ + 1) + tid] = excl;
  if (tid == 0) cstart_g[b * (G_ * G_ + 1) + G_ * G_] = N_;
  __syncthreads();
  for (int i = tid; i < N_; i += 256) {
    int c = cidv[i];
    int pos = atomicAdd(&cur[c], 1);
    spts_g[b * N_ + pos] = p[i];
    skey_g[b * N_ + pos] = (i << 16) | pos;   // (orig_idx:16 | sorted_pos:16)
  }
}

// 8-way merge of sorted 10-lists; writes keylos to dst, returns last (10th) key.
__device__ __forceinline__ unsigned long long merge10(
    const unsigned long long* __restrict__ pub, int base, int* __restrict__ dst) {
  int cc[TPQ];
#pragma unroll
  for (int tt = 0; tt < TPQ; ++tt) cc[tt] = 0;
  unsigned long long last = 0ull;
#pragma unroll
  for (int ss = 0; ss < K_; ++ss) {
    unsigned long long best = ~0ull;
    int bt = 0;
#pragma unroll
    for (int tt = 0; tt < TPQ; ++tt) {
      const int cct = cc[tt];
      unsigned long long h = pub[base + tt * K_ + (cct < K_ ? cct : K_ - 1)];
      if (cct >= K_) h = ~0ull;
      const bool take = h < best;
      best = take ? h : best;
      bt = take ? tt : bt;
    }
    dst[ss] = (int)(unsigned)(best & 0xffffffffull);
    last = best;
#pragma unroll
    for (int tt = 0; tt < TPQ; ++tt) cc[tt] += (bt == tt) ? 1 : 0;
  }
  return last;
}

// ---------------------------------------------------------------------------
// Kernel C: grid-pruned exact KNN (single 5x5 box pass + rare exact retry)
// + stable coord sorts + fused affine. grid = (32 chunks, 32 batches), 256 thr.
// ---------------------------------------------------------------------------
__global__ __launch_bounds__(QPB * TPQ, 4) void conv_knn(
    const float2* __restrict__ spts_g, const int* __restrict__ skey_g,
    const int* __restrict__ cstart_g, const float* __restrict__ Meff,
    float* __restrict__ out) {
  __shared__ float2 spts[N_];                 // 8 KB sorted coords
  __shared__ int    skey[N_];                 // 4 KB (orig<<16)|spos
  __shared__ int    cstart[G_ * G_ + 1];
  __shared__ int    midx[QPB * K_];
  __shared__ int    qdone[QPB];
  __shared__ int    bflag;
  __shared__ __align__(16) float smem[NFEAT * H_];  // publish scratch, later M

  const int b = blockIdx.y, tid = threadIdx.x;
  const int q = tid >> 3, t = tid & 7;
  const int sbase = blockIdx.x * QPB;
  const int s = sbase + q;
  const bool valid = (s < N_);

  const float2* spg = spts_g + (size_t)b * N_;
  const int*    skg = skey_g + (size_t)b * N_;
  for (int i = tid; i < N_; i += QPB * TPQ) { spts[i] = spg[i]; skey[i] = skg[i]; }
  for (int i = tid; i < G_ * G_ + 1; i += QPB * TPQ)
    cstart[i] = cstart_g[b * (G_ * G_ + 1) + i];
  if (tid < QPB) qdone[tid] = (sbase + tid >= N_) ? 1 : 0;
  __syncthreads();

  float px = 0.f, py = 0.f;
  int cx = 0, cy = 0;
  if (valid) {
    px = spts[s].x; py = spts[s].y;
    cx = min(G_ - 1, max(0, (int)(px * (float)G_)));
    cy = min(G_ - 1, max(0, (int)(py * (float)G_)));
  }

  unsigned long long bk[K_];
#pragma unroll
  for (int k = 0; k < K_; ++k) bk[k] = ~0ull;

  unsigned long long* pub = (unsigned long long*)smem;

// branchless rank-insert of sorted point j into bk[] (u64 keys => exact
// (d, orig_idx) lex order, scan-order independent)
#define INSERT(j)                                                              \
  {                                                                            \
    const float2 pp = spts[(j)];                                               \
    const float dx = __fsub_rn(px, pp.x);                                      \
    const float dy = __fsub_rn(py, pp.y);                                      \
    const float dd = __fadd_rn(__fmul_rn(dx, dx), __fmul_rn(dy, dy));          \
    const unsigned long long key =                                             \
        ((unsigned long long)__float_as_uint(dd) << 32) | (unsigned)skey[(j)]; \
    bool c[K_];                                                                \
    _Pragma("unroll") for (int kk = 0; kk < K_; ++kk) c[kk] = key < bk[kk];    \
    _Pragma("unroll") for (int kk = K_ - 1; kk >= 1; --kk)                     \
        bk[kk] = c[kk - 1] ? bk[kk - 1] : (c[kk] ? key : bk[kk]);              \
    bk[0] = c[0] ? key : bk[0];                                                \
  }

  // ---- single-pass 5x5 box scan (rows are contiguous in sorted order) ----
  const int X0 = max(cx - RING0, 0), X1 = min(cx + RING0, G_ - 1);
  const int Y0 = max(cy - RING0, 0), Y1 = min(cy + RING0, G_ - 1);
  if (valid) {
    for (int yy = Y0; yy <= Y1; ++yy) {
      const int s0 = cstart[yy * G_ + X0];
      const int s1 = cstart[yy * G_ + X1 + 1];
      for (int j = s0 + t; j < s1; j += TPQ) INSERT(j);
    }
#pragma unroll
    for (int e = 0; e < K_; ++e) pub[q * PSTR + t * K_ + e] = bk[e];
  }
  __syncthreads();

  // ---- merge + exact termination test (lane t==0 per query) ----
  if (t == 0 && valid) {
    const unsigned long long last = merge10(pub, q * PSTR, &midx[q * K_]);
    const bool have10 = (last != ~0ull);
    const float tau = __uint_as_float((unsigned)(last >> 32));
    float R = 1e30f;
    if (X0 > 0)      R = fminf(R, px - (float)X0 * CW);
    if (X1 < G_ - 1) R = fminf(R, (float)(X1 + 1) * CW - px);
    if (Y0 > 0)      R = fminf(R, py - (float)Y0 * CW);
    if (Y1 < G_ - 1) R = fminf(R, (float)(Y1 + 1) * CW - py);
    const bool fullg = (X0 == 0) && (X1 == G_ - 1) && (Y0 == 0) && (Y1 == G_ - 1);
    const float Rs = R - 1e-6f;   // margin vs. cell-assignment rounding
    qdone[q] = (fullg || (have10 && Rs > 0.f && tau < Rs * Rs)) ? 1 : 0;
  }
  __syncthreads();
  if (tid == 0) {
    int f = 0;
    for (int qq = 0; qq < QPB; ++qq) f |= (qdone[qq] == 0) ? 1 : 0;
    bflag = f;
  }
  __syncthreads();

  // ---- rare exact retry: full brute-force scan for unfinished queries ----
  if (bflag) {
    const bool redo = valid && (qdone[q] == 0);
    if (redo) {
#pragma unroll
      for (int k = 0; k < K_; ++k) bk[k] = ~0ull;
      for (int j = t; j < N_; j += TPQ) INSERT(j);
#pragma unroll
      for (int e = 0; e < K_; ++e) pub[q * PSTR + t * K_ + e] = bk[e];
    }
    __syncthreads();
    if (t == 0 && redo) merge10(pub, q * PSTR, &midx[q * K_]);
    __syncthreads();
  }
#undef INSERT

  // ---- load M (overwrites publish scratch) ----
  for (int i = tid; i < NFEAT * H_; i += QPB * TPQ) smem[i] = Meff[i];

  // ---- gather coords + stable bubble sorts + feature vector ----
  float feat[NFEAT] = {};
  if (valid) {
    float cx1[K_], cy1[K_], cx2[K_], cy2[K_];
#pragma unroll
    for (int k = 0; k < K_; ++k) {
      const int spos = midx[q * K_ + k] & 0xffff;
      const float2 c = spts[spos];
      cx1[k] = c.x; cy1[k] = c.y;
      cx2[k] = c.x; cy2[k] = c.y;
    }
#pragma unroll
    for (int p = 0; p < K_ - 1; ++p) {
#pragma unroll
      for (int u = 0; u < K_ - 1 - p; ++u) {
        const bool sw = cx1[u + 1] < cx1[u];   // strict => stable
        const float tx = sw ? cx1[u] : cx1[u + 1];
        const float ty = sw ? cy1[u] : cy1[u + 1];
        cx1[u]     = sw ? cx1[u + 1] : cx1[u];
        cy1[u]     = sw ? cy1[u + 1] : cy1[u];
        cx1[u + 1] = tx; cy1[u + 1] = ty;
      }
    }
#pragma unroll
    for (int p = 0; p < K_ - 1; ++p) {
#pragma unroll
      for (int u = 0; u < K_ - 1 - p; ++u) {
        const bool sw = cy2[u + 1] < cy2[u];
        const float tx = sw ? cx2[u] : cx2[u + 1];
        const float ty = sw ? cy2[u] : cy2[u + 1];
        cx2[u]     = sw ? cx2[u + 1] : cx2[u];
        cy2[u]     = sw ? cy2[u + 1] : cy2[u];
        cx2[u + 1] = tx; cy2[u + 1] = ty;
      }
    }
#pragma unroll
    for (int k = 0; k < K_; ++k) {
      feat[2 * k]          = cx1[k];
      feat[2 * k + 1]      = cy1[k];
      feat[20 + 2 * k]     = cx2[k];
      feat[20 + 2 * k + 1] = cy2[k];
    }
    feat[40] = px;
    feat[41] = py;
    feat[42] = 1.f;
  }
  __syncthreads();

  // ---- fused affine: each thread = 4 queries x 4 outputs (float4 M + shfl) ----
  const int qset = tid >> 5;
  const int gset = tid & 31;
  float4 acc[4];
#pragma unroll
  for (int j = 0; j < 4; ++j) acc[j] = make_float4(0.f, 0.f, 0.f, 0.f);
#pragma unroll
  for (int r = 0; r < NFEAT; ++r) {
    const float4 m4 = *(const float4*)&smem[r * H_ + gset * 4];
#pragma unroll
    for (int j = 0; j < 4; ++j) {
      const int lsrc = ((qset & 1) * 4 + j) * 8;
      const float fr = __shfl(feat[r], lsrc, 64);
      acc[j].x = fmaf(fr, m4.x, acc[j].x);
      acc[j].y = fmaf(fr, m4.y, acc[j].y);
      acc[j].z = fmaf(fr, m4.z, acc[j].z);
      acc[j].w = fmaf(fr, m4.w, acc[j].w);
    }
  }
#pragma unroll
  for (int j = 0; j < 4; ++j) {
    const int qtar = qset * 4 + j;
    const int star = sbase + qtar;
    if (star < N_) {
      const int otar = skey[star] >> 16;
      *(float4*)&out[((size_t)(b * N_ + otar)) * H_ + gset * 4] = acc[j];
    }
  }
}

// ---------------------------------------------------------------------------
// Fallback (round-2 kernel) if workspace is too small for the grid path.
// ---------------------------------------------------------------------------
#define LSTRIDE 170
__global__ __launch_bounds__(QPB * TPQ, 4) void conv_emb_fb(
    const float* __restrict__ x, const float* __restrict__ Meff,
    float* __restrict__ out) {
  __shared__ float2 pts[N_];
  __shared__ float  smem[NFEAT * H_];
  __shared__ int    midx[QPB * K_];

  const int b   = blockIdx.y;
  const int tid = threadIdx.x;
  const int q   = tid >> 3;
  const int t   = tid & 7;
  const int n   = blockIdx.x * QPB + q;
  const bool valid = (n < N_);

  const float2* xb = (const float2*)(x + (size_t)b * N_ * C_);
  for (int i = tid; i < N_; i += QPB * TPQ) pts[i] = xb[i];
  __syncthreads();

  float px = 0.f, py = 0.f;
  if (valid) { px = pts[n].x; py = pts[n].y; }

  float bd[K_]; int bi[K_];
#pragma unroll
  for (int k = 0; k < K_; ++k) { bd[k] = FLT_MAX; bi[k] = 0; }

#pragma unroll 2
  for (int m = 0; m < N_ / TPQ; ++m) {
    const int j = t + m * TPQ;
    const float2 p = pts[j];
    const float dx = __fsub_rn(px, p.x);
    const float dy = __fsub_rn(py, p.y);
    const float d  = __fadd_rn(__fmul_rn(dx, dx), __fmul_rn(dy, dy));
    bool c[K_];
#pragma unroll
    for (int s = 0; s < K_; ++s) c[s] = d < bd[s];
#pragma unroll
    for (int s = K_ - 1; s >= 1; --s) {
      bd[s] = c[s - 1] ? bd[s - 1] : (c[s] ? d : bd[s]);
      bi[s] = c[s - 1] ? bi[s - 1] : (c[s] ? j : bi[s]);
    }
    bd[0] = c[0] ? d : bd[0];
    bi[0] = c[0] ? j : bi[0];
  }

  const int lbase = q * LSTRIDE + t * 2 * K_;
#pragma unroll
  for (int e = 0; e < K_; ++e) {
    smem[lbase + 2 * e]     = bd[e];
    smem[lbase + 2 * e + 1] = __int_as_float(bi[e]);
  }
  __syncthreads();

  if (t == 0 && valid) {
    int cc[TPQ];
#pragma unroll
    for (int tt = 0; tt < TPQ; ++tt) cc[tt] = 0;
    const int mb = q * LSTRIDE;
#pragma unroll
    for (int s = 0; s < K_; ++s) {
      float bdv = FLT_MAX; int biv = 0x7fffffff; int bt = 0;
#pragma unroll
      for (int tt = 0; tt < TPQ; ++tt) {
        const int off = mb + tt * 2 * K_ + cc[tt] * 2;
        const float hd = smem[off];
        const int   hi = __float_as_int(smem[off + 1]);
        const bool take = (hd < bdv) || ((hd == bdv) && (hi < biv));
        bdv = take ? hd : bdv;
        biv = take ? hi : biv;
        bt  = take ? tt : bt;
      }
      midx[q * K_ + s] = biv;
#pragma unroll
      for (int tt = 0; tt < TPQ; ++tt) cc[tt] += (bt == tt) ? 1 : 0;
    }
  }
  __syncthreads();

  int ridx[K_];
  if (valid) {
#pragma unroll
    for (int k = 0; k < K_; ++k) ridx[k] = midx[q * K_ + k];
  }
  for (int i = tid; i < NFEAT * H_; i += QPB * TPQ) smem[i] = Meff[i];

  float feat[NFEAT];
  if (valid) {
    float cx1[K_], cy1[K_], cx2[K_], cy2[K_];
#pragma unroll
    for (int k = 0; k < K_; ++k) {
      const float2 c = pts[ridx[k]];
      cx1[k] = c.x; cy1[k] = c.y;
      cx2[k] = c.x; cy2[k] = c.y;
    }
#pragma unroll
    for (int p = 0; p < K_ - 1; ++p) {
#pragma unroll
      for (int s2 = 0; s2 < K_ - 1 - p; ++s2) {
        const bool sw = cx1[s2 + 1] < cx1[s2];
        const float tx = sw ? cx1[s2] : cx1[s2 + 1];
        const float ty = sw ? cy1[s2] : cy1[s2 + 1];
        cx1[s2]     = sw ? cx1[s2 + 1] : cx1[s2];
        cy1[s2]     = sw ? cy1[s2 + 1] : cy1[s2];
        cx1[s2 + 1] = tx; cy1[s2 + 1] = ty;
      }
    }
#pragma unroll
    for (int p = 0; p < K_ - 1; ++p) {
#pragma unroll
      for (int s2 = 0; s2 < K_ - 1 - p; ++s2) {
        const bool sw = cy2[s2 + 1] < cy2[s2];
        const float tx = sw ? cx2[s2] : cx2[s2 + 1];
        const float ty = sw ? cy2[s2] : cy2[s2 + 1];
        cx2[s2]     = sw ? cx2[s2 + 1] : cx2[s2];
        cy2[s2]     = sw ? cy2[s2 + 1] : cy2[s2];
        cx2[s2 + 1] = tx; cy2[s2 + 1] = ty;
      }
    }
#pragma unroll
    for (int k = 0; k < K_; ++k) {
      feat[2 * k]          = cx1[k];
      feat[2 * k + 1]      = cy1[k];
      feat[20 + 2 * k]     = cx2[k];
      feat[20 + 2 * k + 1] = cy2[k];
    }
    feat[40] = px;
    feat[41] = py;
    feat[42] = 1.f;
  }
  __syncthreads();

  if (valid) {
    float* op = out + ((size_t)(b * N_ + n)) * H_;
#pragma unroll 2
    for (int gi = 0; gi < H_ / TPQ; ++gi) {
      const int g = gi * TPQ + t;
      float acc = 0.f;
#pragma unroll
      for (int r = 0; r < NFEAT; ++r)
        acc = fmaf(feat[r], smem[r * H_ + g], acc);
      op[g] = acc;
    }
  }
}

extern "C" void kernel_launch(void* const* d_in, const int* in_sizes, int n_in,
                              void* d_out, int out_size, void* d_ws, size_t ws_size,
                              hipStream_t stream) {
  const float* x  = (const float*)d_in[0];
  const float* Wx = (const float*)d_in[1];
  const float* bx = (const float*)d_in[2];
  const float* Wy = (const float*)d_in[3];
  const float* by = (const float*)d_in[4];
  const float* W1 = (const float*)d_in[5];
  const float* b1 = (const float*)d_in[6];
  const float* W2 = (const float*)d_in[7];
  const float* b2 = (const float*)d_in[8];
  float* o = (float*)d_out;

  char* ws = (char*)d_ws;
  float* Meff = (float*)(ws + WS_MEFF);

  build_meff<<<dim3(NFEAT), dim3(H_), 0, stream>>>(Wx, bx, Wy, by, W1, b1, W2, b2, Meff);

  if (ws_size >= WS_NEED) {
    float2* spts_g  = (float2*)(ws + WS_SPTS);
    int*   skey_g   = (int*)(ws + WS_SKEY);
    int*   cstart_g = (int*)(ws + WS_CSTART);
    build_grid<<<dim3(B_), dim3(256), 0, stream>>>(x, spts_g, skey_g, cstart_g);
    conv_knn<<<dim3((N_ + QPB - 1) / QPB, B_), dim3(QPB * TPQ), 0, stream>>>(
        spts_g, skey_g, cstart_g, Meff, o);
  } else {
    conv_emb_fb<<<dim3((N_ + QPB - 1) / QPB, B_), dim3(QPB * TPQ), 0, stream>>>(x, Meff, o);
  }
}

// Round 5
// 44.033 us; speedup vs baseline: 6.0877x; 5.9516x over previous
//
#include <hip/hip_runtime.h>
#include <cfloat>

#define B_ 32
#define N_ 1000
#define K_ 10
#define H_ 128
#define C_ 2
#define NFEAT 43    // 20 sortedX + 20 sortedY + 2 coords + 1 bias
#define QPB 32      // queries per block
#define TPQ 8       // threads per query
#define G_ 16       // grid cells per axis
#define CW (1.0f / 16.0f)
#define RING0 2     // box half-width in cells (5x5)
#define PSTR 81     // u64 stride per query in publish scratch

// ws layout (bytes): [0,22016) Meff | [22016,278016) spts float2 | [278016,406016) skey int
//                    | [406016,438912) cellstart int
#define WS_MEFF   0
#define WS_SPTS   22016
#define WS_SKEY   278016
#define WS_CSTART 406016
#define WS_NEED   438912

// ---------------------------------------------------------------------------
// Kernel A: fused affine map M[43][128] (folds Wx,Wy,W1,W2,biases).
// ---------------------------------------------------------------------------
__global__ __launch_bounds__(H_) void build_meff(
    const float* __restrict__ Wx, const float* __restrict__ bx,
    const float* __restrict__ Wy, const float* __restrict__ by,
    const float* __restrict__ W1, const float* __restrict__ b1,
    const float* __restrict__ W2, const float* __restrict__ b2,
    float* __restrict__ M) {
  const int r = blockIdx.x;
  const int g = threadIdx.x;
  float acc = 0.f;
  if (r < 40) {
    const int rp = (r < 20) ? r : r - 20;
    const float* W = (r < 20) ? Wx : Wy;
    const int k = rp >> 1;
    const int c = rp & 1;
    const float* Wcol = W + c * K_ + k;     // h-stride = C_*K_
    for (int h = 0; h < H_; ++h)
      acc = fmaf(Wcol[h * C_ * K_], W2[h * H_ + g], acc);
  } else if (r < 42) {
    acc = W1[(r - 40) * H_ + g];
  } else {
    for (int h = 0; h < H_; ++h)
      acc = fmaf(bx[h] + by[h], W2[h * H_ + g], acc);
    acc += b1[g] + b2[g];
  }
  M[r * H_ + g] = acc;
}

// ---------------------------------------------------------------------------
// Kernel B: per-batch counting sort of points into 16x16 cells.
// ---------------------------------------------------------------------------
__global__ __launch_bounds__(256) void build_grid(
    const float* __restrict__ x, float2* __restrict__ spts_g,
    int* __restrict__ skey_g, int* __restrict__ cstart_g) {
  const int b = blockIdx.x, tid = threadIdx.x;
  __shared__ float2 p[N_];
  __shared__ short  cidv[N_];
  __shared__ int    hist[G_ * G_], scn[G_ * G_], cur[G_ * G_];

  const float2* xb = (const float2*)(x + (size_t)b * N_ * C_);
  hist[tid] = 0;
  __syncthreads();
  for (int i = tid; i < N_; i += 256) {
    float2 v = xb[i];
    p[i] = v;
    int cxx = min(G_ - 1, max(0, (int)(v.x * (float)G_)));
    int cyy = min(G_ - 1, max(0, (int)(v.y * (float)G_)));
    int c = cyy * G_ + cxx;
    cidv[i] = (short)c;
    atomicAdd(&hist[c], 1);
  }
  __syncthreads();
  const int v = hist[tid];
  scn[tid] = v;
  __syncthreads();
  for (int off = 1; off < G_ * G_; off <<= 1) {
    int add = (tid >= off) ? scn[tid - off] : 0;
    __syncthreads();
    scn[tid] += add;
    __syncthreads();
  }
  const int excl = scn[tid] - v;
  cur[tid] = excl;
  cstart_g[b * (G_ * G_ + 1) + tid] = excl;
  if (tid == 0) cstart_g[b * (G_ * G_ + 1) + G_ * G_] = N_;
  __syncthreads();
  for (int i = tid; i < N_; i += 256) {
    int c = cidv[i];
    int pos = atomicAdd(&cur[c], 1);
    spts_g[b * N_ + pos] = p[i];
    skey_g[b * N_ + pos] = (i << 16) | pos;   // (orig_idx:16 | sorted_pos:16)
  }
}

// 8-way merge of sorted 10-lists; writes keylos to dst, returns last (10th) key.
__device__ __forceinline__ unsigned long long merge10(
    const unsigned long long* __restrict__ pub, int base, int* __restrict__ dst) {
  int cc[TPQ];
#pragma unroll
  for (int tt = 0; tt < TPQ; ++tt) cc[tt] = 0;
  unsigned long long last = 0ull;
#pragma unroll
  for (int ss = 0; ss < K_; ++ss) {
    unsigned long long best = ~0ull;
    int bt = 0;
#pragma unroll
    for (int tt = 0; tt < TPQ; ++tt) {
      const int cct = cc[tt];
      unsigned long long h = pub[base + tt * K_ + (cct < K_ ? cct : K_ - 1)];
      if (cct >= K_) h = ~0ull;
      const bool take = h < best;
      best = take ? h : best;
      bt = take ? tt : bt;
    }
    dst[ss] = (int)(unsigned)(best & 0xffffffffull);
    last = best;
#pragma unroll
    for (int tt = 0; tt < TPQ; ++tt) cc[tt] += (bt == tt) ? 1 : 0;
  }
  return last;
}

// ---------------------------------------------------------------------------
// Kernel C: grid-pruned exact KNN (5x5 box + rare exact retry) + in-feat
// stable sorts + fb-style low-pressure affine. grid = (32, 32), 256 thr.
// ---------------------------------------------------------------------------
__global__ __launch_bounds__(QPB * TPQ, 4) void conv_knn(
    const float2* __restrict__ spts_g, const int* __restrict__ skey_g,
    const int* __restrict__ cstart_g, const float* __restrict__ Meff,
    float* __restrict__ out) {
  __shared__ float2 spts[N_];                 // 8 KB sorted coords
  __shared__ int    skey[N_];                 // 4 KB (orig<<16)|spos
  __shared__ int    cstart[G_ * G_ + 1];
  __shared__ int    midx[QPB * K_];
  __shared__ int    qdone[QPB];
  __shared__ int    bflag;
  __shared__ __align__(16) float smem[NFEAT * H_];  // publish scratch, later M

  const int b = blockIdx.y, tid = threadIdx.x;
  const int q = tid >> 3, t = tid & 7;
  const int sbase = blockIdx.x * QPB;
  const int s = sbase + q;
  const bool valid = (s < N_);

  const float2* spg = spts_g + (size_t)b * N_;
  const int*    skg = skey_g + (size_t)b * N_;
  for (int i = tid; i < N_; i += QPB * TPQ) { spts[i] = spg[i]; skey[i] = skg[i]; }
  for (int i = tid; i < G_ * G_ + 1; i += QPB * TPQ)
    cstart[i] = cstart_g[b * (G_ * G_ + 1) + i];
  if (tid < QPB) qdone[tid] = (sbase + tid >= N_) ? 1 : 0;
  __syncthreads();

  float px = 0.f, py = 0.f;
  int cx = 0, cy = 0;
  if (valid) {
    px = spts[s].x; py = spts[s].y;
    cx = min(G_ - 1, max(0, (int)(px * (float)G_)));
    cy = min(G_ - 1, max(0, (int)(py * (float)G_)));
  }

  unsigned long long bk[K_];
#pragma unroll
  for (int k = 0; k < K_; ++k) bk[k] = ~0ull;

  unsigned long long* pub = (unsigned long long*)smem;

// branchless rank-insert of sorted point j into bk[] (u64 key = (d2,orig,spos)
// => exact lax.top_k (d, lower-orig) semantics, scan-order independent)
#define INSERT(j)                                                              \
  {                                                                            \
    const float2 pp = spts[(j)];                                               \
    const float dx = __fsub_rn(px, pp.x);                                      \
    const float dy = __fsub_rn(py, pp.y);                                      \
    const float dd = __fadd_rn(__fmul_rn(dx, dx), __fmul_rn(dy, dy));          \
    const unsigned long long key =                                             \
        ((unsigned long long)__float_as_uint(dd) << 32) | (unsigned)skey[(j)]; \
    bool c[K_];                                                                \
    _Pragma("unroll") for (int kk = 0; kk < K_; ++kk) c[kk] = key < bk[kk];    \
    _Pragma("unroll") for (int kk = K_ - 1; kk >= 1; --kk)                     \
        bk[kk] = c[kk - 1] ? bk[kk - 1] : (c[kk] ? key : bk[kk]);              \
    bk[0] = c[0] ? key : bk[0];                                                \
  }

  // ---- single-pass 5x5 box scan (each row contiguous in sorted order) ----
  const int X0 = max(cx - RING0, 0), X1 = min(cx + RING0, G_ - 1);
  const int Y0 = max(cy - RING0, 0), Y1 = min(cy + RING0, G_ - 1);
  if (valid) {
    for (int yy = Y0; yy <= Y1; ++yy) {
      const int s0 = cstart[yy * G_ + X0];
      const int s1 = cstart[yy * G_ + X1 + 1];
      for (int j = s0 + t; j < s1; j += TPQ) INSERT(j);
    }
#pragma unroll
    for (int e = 0; e < K_; ++e) pub[q * PSTR + t * K_ + e] = bk[e];
  }
  __syncthreads();

  // ---- merge + exact termination test (lane t==0 per query) ----
  if (t == 0 && valid) {
    const unsigned long long last = merge10(pub, q * PSTR, &midx[q * K_]);
    const bool have10 = (last != ~0ull);
    const float tau = __uint_as_float((unsigned)(last >> 32));
    float R = 1e30f;
    if (X0 > 0)      R = fminf(R, px - (float)X0 * CW);
    if (X1 < G_ - 1) R = fminf(R, (float)(X1 + 1) * CW - px);
    if (Y0 > 0)      R = fminf(R, py - (float)Y0 * CW);
    if (Y1 < G_ - 1) R = fminf(R, (float)(Y1 + 1) * CW - py);
    const bool fullg = (X0 == 0) && (X1 == G_ - 1) && (Y0 == 0) && (Y1 == G_ - 1);
    const float Rs = R - 1e-6f;   // margin vs. cell-assignment rounding
    qdone[q] = (fullg || (have10 && Rs > 0.f && tau < Rs * Rs)) ? 1 : 0;
  }
  __syncthreads();
  if (tid == 0) {
    int f = 0;
    for (int qq = 0; qq < QPB; ++qq) f |= (qdone[qq] == 0) ? 1 : 0;
    bflag = f;
  }
  __syncthreads();

  // ---- rare exact retry: full brute-force scan for unfinished queries ----
  if (bflag) {
    const bool redo = valid && (qdone[q] == 0);
    if (redo) {
#pragma unroll
      for (int k = 0; k < K_; ++k) bk[k] = ~0ull;
      for (int j = t; j < N_; j += TPQ) INSERT(j);
#pragma unroll
      for (int e = 0; e < K_; ++e) pub[q * PSTR + t * K_ + e] = bk[e];
    }
    __syncthreads();
    if (t == 0 && redo) merge10(pub, q * PSTR, &midx[q * K_]);
    __syncthreads();
  }
#undef INSERT

  // ---- load M (overwrites publish scratch; all lists consumed) ----
  for (int i = tid; i < NFEAT * H_; i += QPB * TPQ) smem[i] = Meff[i];

  // ---- gather coords directly into feat + in-place stable bubble sorts ----
  // (all 8 lanes of a query compute feat redundantly; keeps pressure low)
  float feat[NFEAT];
  if (valid) {
#pragma unroll
    for (int k = 0; k < K_; ++k) {
      const int spos = midx[q * K_ + k] & 0xffff;
      const float2 c = spts[spos];
      feat[2 * k]          = c.x;
      feat[2 * k + 1]      = c.y;
      feat[20 + 2 * k]     = c.x;
      feat[20 + 2 * k + 1] = c.y;
    }
    // sort pairs feat[2k],feat[2k+1] by x = feat[2k]  (strict swap => stable)
#pragma unroll
    for (int p = 0; p < K_ - 1; ++p) {
#pragma unroll
      for (int u = 0; u < K_ - 1 - p; ++u) {
        const bool sw = feat[2 * u + 2] < feat[2 * u];
        const float ax = feat[2 * u], ay = feat[2 * u + 1];
        feat[2 * u]     = sw ? feat[2 * u + 2] : ax;
        feat[2 * u + 1] = sw ? feat[2 * u + 3] : ay;
        feat[2 * u + 2] = sw ? ax : feat[2 * u + 2];
        feat[2 * u + 3] = sw ? ay : feat[2 * u + 3];
      }
    }
    // sort pairs feat[20+2k],feat[20+2k+1] by y = feat[20+2k+1]
#pragma unroll
    for (int p = 0; p < K_ - 1; ++p) {
#pragma unroll
      for (int u = 0; u < K_ - 1 - p; ++u) {
        const int e = 20 + 2 * u;
        const bool sw = feat[e + 3] < feat[e + 1];
        const float ax = feat[e], ay = feat[e + 1];
        feat[e]     = sw ? feat[e + 2] : ax;
        feat[e + 1] = sw ? feat[e + 3] : ay;
        feat[e + 2] = sw ? ax : feat[e + 2];
        feat[e + 3] = sw ? ay : feat[e + 3];
      }
    }
    feat[40] = px;
    feat[41] = py;
    feat[42] = 1.f;
  }
  __syncthreads();

  // ---- fb-style affine: own query, 16 outputs, broadcast LDS reads ----
  if (valid) {
    const int otar = skey[s] >> 16;
    float* op = out + ((size_t)(b * N_ + otar)) * H_;
#pragma unroll 2
    for (int gi = 0; gi < H_ / TPQ; ++gi) {
      const int g = gi * TPQ + t;
      float acc = 0.f;
#pragma unroll
      for (int r = 0; r < NFEAT; ++r)
        acc = fmaf(feat[r], smem[r * H_ + g], acc);
      op[g] = acc;
    }
  }
}

// ---------------------------------------------------------------------------
// Fallback (round-2 kernel) if workspace is too small for the grid path.
// ---------------------------------------------------------------------------
#define LSTRIDE 170
__global__ __launch_bounds__(QPB * TPQ, 4) void conv_emb_fb(
    const float* __restrict__ x, const float* __restrict__ Meff,
    float* __restrict__ out) {
  __shared__ float2 pts[N_];
  __shared__ float  smem[NFEAT * H_];
  __shared__ int    midx[QPB * K_];

  const int b   = blockIdx.y;
  const int tid = threadIdx.x;
  const int q   = tid >> 3;
  const int t   = tid & 7;
  const int n   = blockIdx.x * QPB + q;
  const bool valid = (n < N_);

  const float2* xb = (const float2*)(x + (size_t)b * N_ * C_);
  for (int i = tid; i < N_; i += QPB * TPQ) pts[i] = xb[i];
  __syncthreads();

  float px = 0.f, py = 0.f;
  if (valid) { px = pts[n].x; py = pts[n].y; }

  float bd[K_]; int bi[K_];
#pragma unroll
  for (int k = 0; k < K_; ++k) { bd[k] = FLT_MAX; bi[k] = 0; }

#pragma unroll 2
  for (int m = 0; m < N_ / TPQ; ++m) {
    const int j = t + m * TPQ;
    const float2 p = pts[j];
    const float dx = __fsub_rn(px, p.x);
    const float dy = __fsub_rn(py, p.y);
    const float d  = __fadd_rn(__fmul_rn(dx, dx), __fmul_rn(dy, dy));
    bool c[K_];
#pragma unroll
    for (int s = 0; s < K_; ++s) c[s] = d < bd[s];
#pragma unroll
    for (int s = K_ - 1; s >= 1; --s) {
      bd[s] = c[s - 1] ? bd[s - 1] : (c[s] ? d : bd[s]);
      bi[s] = c[s - 1] ? bi[s - 1] : (c[s] ? j : bi[s]);
    }
    bd[0] = c[0] ? d : bd[0];
    bi[0] = c[0] ? j : bi[0];
  }

  const int lbase = q * LSTRIDE + t * 2 * K_;
#pragma unroll
  for (int e = 0; e < K_; ++e) {
    smem[lbase + 2 * e]     = bd[e];
    smem[lbase + 2 * e + 1] = __int_as_float(bi[e]);
  }
  __syncthreads();

  if (t == 0 && valid) {
    int cc[TPQ];
#pragma unroll
    for (int tt = 0; tt < TPQ; ++tt) cc[tt] = 0;
    const int mb = q * LSTRIDE;
#pragma unroll
    for (int s = 0; s < K_; ++s) {
      float bdv = FLT_MAX; int biv = 0x7fffffff; int bt = 0;
#pragma unroll
      for (int tt = 0; tt < TPQ; ++tt) {
        const int off = mb + tt * 2 * K_ + cc[tt] * 2;
        const float hd = smem[off];
        const int   hi = __float_as_int(smem[off + 1]);
        const bool take = (hd < bdv) || ((hd == bdv) && (hi < biv));
        bdv = take ? hd : bdv;
        biv = take ? hi : biv;
        bt  = take ? tt : bt;
      }
      midx[q * K_ + s] = biv;
#pragma unroll
      for (int tt = 0; tt < TPQ; ++tt) cc[tt] += (bt == tt) ? 1 : 0;
    }
  }
  __syncthreads();

  int ridx[K_];
  if (valid) {
#pragma unroll
    for (int k = 0; k < K_; ++k) ridx[k] = midx[q * K_ + k];
  }
  for (int i = tid; i < NFEAT * H_; i += QPB * TPQ) smem[i] = Meff[i];

  float feat[NFEAT];
  if (valid) {
#pragma unroll
    for (int k = 0; k < K_; ++k) {
      const float2 c = pts[ridx[k]];
      feat[2 * k]          = c.x;
      feat[2 * k + 1]      = c.y;
      feat[20 + 2 * k]     = c.x;
      feat[20 + 2 * k + 1] = c.y;
    }
#pragma unroll
    for (int p = 0; p < K_ - 1; ++p) {
#pragma unroll
      for (int u = 0; u < K_ - 1 - p; ++u) {
        const bool sw = feat[2 * u + 2] < feat[2 * u];
        const float ax = feat[2 * u], ay = feat[2 * u + 1];
        feat[2 * u]     = sw ? feat[2 * u + 2] : ax;
        feat[2 * u + 1] = sw ? feat[2 * u + 3] : ay;
        feat[2 * u + 2] = sw ? ax : feat[2 * u + 2];
        feat[2 * u + 3] = sw ? ay : feat[2 * u + 3];
      }
    }
#pragma unroll
    for (int p = 0; p < K_ - 1; ++p) {
#pragma unroll
      for (int u = 0; u < K_ - 1 - p; ++u) {
        const int e = 20 + 2 * u;
        const bool sw = feat[e + 3] < feat[e + 1];
        const float ax = feat[e], ay = feat[e + 1];
        feat[e]     = sw ? feat[e + 2] : ax;
        feat[e + 1] = sw ? feat[e + 3] : ay;
        feat[e + 2] = sw ? ax : feat[e + 2];
        feat[e + 3] = sw ? ay : feat[e + 3];
      }
    }
    feat[40] = px;
    feat[41] = py;
    feat[42] = 1.f;
  }
  __syncthreads();

  if (valid) {
    float* op = out + ((size_t)(b * N_ + n)) * H_;
#pragma unroll 2
    for (int gi = 0; gi < H_ / TPQ; ++gi) {
      const int g = gi * TPQ + t;
      float acc = 0.f;
#pragma unroll
      for (int r = 0; r < NFEAT; ++r)
        acc = fmaf(feat[r], smem[r * H_ + g], acc);
      op[g] = acc;
    }
  }
}

extern "C" void kernel_launch(void* const* d_in, const int* in_sizes, int n_in,
                              void* d_out, int out_size, void* d_ws, size_t ws_size,
                              hipStream_t stream) {
  const float* x  = (const float*)d_in[0];
  const float* Wx = (const float*)d_in[1];
  const float* bx = (const float*)d_in[2];
  const float* Wy = (const float*)d_in[3];
  const float* by = (const float*)d_in[4];
  const float* W1 = (const float*)d_in[5];
  const float* b1 = (const float*)d_in[6];
  const float* W2 = (const float*)d_in[7];
  const float* b2 = (const float*)d_in[8];
  float* o = (float*)d_out;

  char* ws = (char*)d_ws;
  float* Meff = (float*)(ws + WS_MEFF);

  build_meff<<<dim3(NFEAT), dim3(H_), 0, stream>>>(Wx, bx, Wy, by, W1, b1, W2, b2, Meff);

  if (ws_size >= WS_NEED) {
    float2* spts_g  = (float2*)(ws + WS_SPTS);
    int*   skey_g   = (int*)(ws + WS_SKEY);
    int*   cstart_g = (int*)(ws + WS_CSTART);
    build_grid<<<dim3(B_), dim3(256), 0, stream>>>(x, spts_g, skey_g, cstart_g);
    conv_knn<<<dim3((N_ + QPB - 1) / QPB, B_), dim3(QPB * TPQ), 0, stream>>>(
        spts_g, skey_g, cstart_g, Meff, o);
  } else {
    conv_emb_fb<<<dim3((N_ + QPB - 1) / QPB, B_), dim3(QPB * TPQ), 0, stream>>>(x, Meff, o);
  }
}